// Round 1
// baseline (790.742 us; speedup 1.0000x reference)
//
#include <hip/hip_runtime.h>
#include <stdint.h>
#include <stddef.h>
#include <type_traits>

// Problem constants (DeepseekV2Attention_15882789061247)
#define TK      2048   // tokens (B*S)
#define HIDDEN  4096   // H*D
#define NHEAD   32
#define NKV     8
#define DH      128
#define NQKVC   6144   // H*D + 2*KVH*D
#define NSLOTS  4096
#define GROUPS  4      // H / KVH

typedef __attribute__((ext_vector_type(8))) short  short8;
typedef __attribute__((ext_vector_type(4))) short  short4v;
typedef __attribute__((ext_vector_type(4))) float  float4v;

__device__ __forceinline__ unsigned short f2bf(float f) {
  union { float f; unsigned u; } v; v.f = f;
  return (unsigned short)((v.u + 0x7FFFu + ((v.u >> 16) & 1u)) >> 16); // RNE
}
__device__ __forceinline__ float bf2f(unsigned short b) {
  union { unsigned u; float f; } v; v.u = ((unsigned)b) << 16;
  return v.f;
}

// ---------------- fp32 -> bf16 elementwise convert (vectorized) -------------
__global__ __launch_bounds__(256) void convert_f32_bf16(
    const float* __restrict__ src, unsigned short* __restrict__ dst, int n4) {
  int i = blockIdx.x * blockDim.x + threadIdx.x;
  int stride = gridDim.x * blockDim.x;
  for (; i < n4; i += stride) {
    float4v v = *(const float4v*)(src + (size_t)i * 4);
    short4v o;
#pragma unroll
    for (int j = 0; j < 4; ++j) o[j] = (short)f2bf(v[j]);
    *(short4v*)(dst + (size_t)i * 4) = o;
  }
}

// ---------------- fp32 [K][N] -> bf16 [N][K] tiled transpose ----------------
__global__ __launch_bounds__(256) void transpose_convert(
    const float* __restrict__ src, unsigned short* __restrict__ dst,
    int K, int N) {
  __shared__ float tile[64][65];
  int k0 = blockIdx.y * 64, n0 = blockIdx.x * 64;
  int tc = threadIdx.x & 63, tr = threadIdx.x >> 6;  // tr in 0..3
#pragma unroll
  for (int i = 0; i < 16; ++i) {
    int r = tr + 4 * i;
    tile[r][tc] = src[(size_t)(k0 + r) * N + n0 + tc];
  }
  __syncthreads();
#pragma unroll
  for (int i = 0; i < 16; ++i) {
    int r = tr + 4 * i;
    dst[(size_t)(n0 + r) * K + k0 + tc] = f2bf(tile[tc][r]);
  }
}

// ---------------- bf16 GEMM: C[M][N] = A[M][K] * BT[N][K]^T -----------------
// 128x128 tile, BK=64, 256 threads (4 waves 2x2), mfma_f32_16x16x32_bf16.
// LDS rows padded to 72 bf16 (144B): 16B-aligned, ~2-way bank aliasing (free).
template <typename OutT>
__global__ __launch_bounds__(256) void gemm_bt(
    const unsigned short* __restrict__ A,   // [M][K] bf16
    const unsigned short* __restrict__ BT,  // [N][K] bf16
    OutT* __restrict__ C,                   // [M][N]
    int M, int N, int K) {
  __shared__ unsigned short As[128][72];
  __shared__ unsigned short Bs[128][72];
  int m0 = blockIdx.y * 128, n0 = blockIdx.x * 128;
  int tid = threadIdx.x;
  int lane = tid & 63, w = tid >> 6;
  int wr = (w >> 1) * 64, wc = (w & 1) * 64;   // wave's 64x64 sub-tile
  int lr = lane & 15, lk = (lane >> 4) * 8;    // fragment row / k-group

  float4v acc[4][4] = {};

  for (int k0 = 0; k0 < K; k0 += 64) {
    // stage A-tile and BT-tile: 128 rows x 64 bf16 each, 16B chunks
#pragma unroll
    for (int i = 0; i < 4; ++i) {
      int c = tid + 256 * i;          // 0..1023
      int row = c >> 3, kc = (c & 7) * 8;
      *(short8*)&As[row][kc] = *(const short8*)(A + (size_t)(m0 + row) * K + k0 + kc);
      *(short8*)&Bs[row][kc] = *(const short8*)(BT + (size_t)(n0 + row) * K + k0 + kc);
    }
    __syncthreads();
#pragma unroll
    for (int kk = 0; kk < 64; kk += 32) {
      short8 a[4], b[4];
#pragma unroll
      for (int mi = 0; mi < 4; ++mi) a[mi] = *(const short8*)&As[wr + mi * 16 + lr][kk + lk];
#pragma unroll
      for (int ni = 0; ni < 4; ++ni) b[ni] = *(const short8*)&Bs[wc + ni * 16 + lr][kk + lk];
#pragma unroll
      for (int mi = 0; mi < 4; ++mi)
#pragma unroll
        for (int ni = 0; ni < 4; ++ni)
          acc[mi][ni] = __builtin_amdgcn_mfma_f32_16x16x32_bf16(a[mi], b[ni], acc[mi][ni], 0, 0, 0);
    }
    __syncthreads();
  }

  // epilogue: C/D layout col = lane&15, row = (lane>>4)*4 + r  [m89-verified]
  int orow = (lane >> 4) * 4;
#pragma unroll
  for (int mi = 0; mi < 4; ++mi)
#pragma unroll
    for (int ni = 0; ni < 4; ++ni)
#pragma unroll
      for (int r = 0; r < 4; ++r) {
        float v = acc[mi][ni][r];
        size_t idx = (size_t)(m0 + wr + mi * 16 + orow + r) * N + n0 + wc + ni * 16 + lr;
        if constexpr (std::is_same<OutT, unsigned short>::value)
          C[idx] = f2bf(v);
        else
          C[idx] = v;
      }
}

// ---------------- RoPE + KV-cache scatter + layout producers ----------------
// One block per token. Reads bf16 qkv row, writes:
//   q bf16 [T][H][D], k bf16 [T][KVH][D], vT bf16 [KVH*D][T],
//   k/v caches fp32 scattered at slots[t].
__global__ __launch_bounds__(256) void rope_scatter(
    const unsigned short* __restrict__ qkv,   // [T][6144]
    const float* __restrict__ cosb,           // [T][64]
    const float* __restrict__ sinb,           // [T][64]
    const int* __restrict__ slots,
    unsigned short* __restrict__ qout,        // [T][4096]
    unsigned short* __restrict__ kout,        // [T][1024]
    unsigned short* __restrict__ vtout,       // [1024][T]
    float* __restrict__ kcache,               // [NSLOTS][1024] (output)
    float* __restrict__ vcache) {             // [NSLOTS][1024] (output)
  int t = blockIdx.x;
  int tid = threadIdx.x;
  int slot = slots[t];
  const unsigned short* row = qkv + (size_t)t * NQKVC;

  // Q: 32 heads * 64 rope pairs = 2048 pairs
#pragma unroll
  for (int i = 0; i < 8; ++i) {
    int p = tid + 256 * i;
    int h = p >> 6, d = p & 63;
    float x1 = bf2f(row[h * 128 + d]);
    float x2 = bf2f(row[h * 128 + d + 64]);
    float c = cosb[t * 64 + d], s = sinb[t * 64 + d];
    qout[(size_t)t * HIDDEN + h * 128 + d]      = f2bf(x1 * c - x2 * s);
    qout[(size_t)t * HIDDEN + h * 128 + d + 64] = f2bf(x2 * c + x1 * s);
  }
  // K: 8 kv-heads * 64 pairs = 512 pairs
#pragma unroll
  for (int i = 0; i < 2; ++i) {
    int p = tid + 256 * i;
    int kh = p >> 6, d = p & 63;
    float x1 = bf2f(row[4096 + kh * 128 + d]);
    float x2 = bf2f(row[4096 + kh * 128 + d + 64]);
    float c = cosb[t * 64 + d], s = sinb[t * 64 + d];
    float o1 = x1 * c - x2 * s, o2 = x2 * c + x1 * s;
    kout[t * 1024 + kh * 128 + d]      = f2bf(o1);
    kout[t * 1024 + kh * 128 + d + 64] = f2bf(o2);
    kcache[(size_t)slot * 1024 + kh * 128 + d]      = o1;
    kcache[(size_t)slot * 1024 + kh * 128 + d + 64] = o2;
  }
  // V: 1024 elements (no rope); also write transposed bf16 [kvh*128+d][t]
#pragma unroll
  for (int i = 0; i < 4; ++i) {
    int e = tid + 256 * i;
    float v = bf2f(row[5120 + e]);
    vcache[(size_t)slot * 1024 + e] = v;
    vtout[(size_t)e * TK + t] = f2bf(v);
  }
}

// ---------------- flash attention (causal, GQA) -----------------------------
// grid (S/64, H); 256 threads = 4 waves, each wave owns 16 q-rows.
// KV tile = 32 rows. Online softmax per lane over 4 q-rows (16-lane reduce).
__global__ __launch_bounds__(256) void attn_kernel(
    const unsigned short* __restrict__ q,    // [T][H][D]
    const unsigned short* __restrict__ k,    // [T][KVH][D]
    const unsigned short* __restrict__ vt,   // [KVH*D][T]
    unsigned short* __restrict__ attn) {     // [T][H*D]
  __shared__ unsigned short Ks[32][136];   // [kv][d], pad->272B rows
  __shared__ unsigned short Vs[128][40];   // [d][kv], pad->80B rows
  __shared__ unsigned short Ps[4][16][40]; // per-wave P, pad->80B rows (16B aligned)

  int q0 = blockIdx.x * 64;
  int h = blockIdx.y;
  int g = h >> 2;                       // kv head = h / GROUPS
  int tid = threadIdx.x, lane = tid & 63, w = tid >> 6;
  int lr = lane & 15, lg = lane >> 4;   // fragment row / k-group idx

  // Q fragments: A-operand, row = lane&15, k = 8*(lane>>4)+e per 32-wide chunk
  short8 qf[4];
  int qrow = q0 + w * 16 + lr;
#pragma unroll
  for (int c = 0; c < 4; ++c)
    qf[c] = *(const short8*)(q + (size_t)qrow * HIDDEN + h * DH + c * 32 + lg * 8);

  float4v accO[8] = {};
  float m[4], l[4];
#pragma unroll
  for (int r = 0; r < 4; ++r) { m[r] = -1e30f; l[r] = 0.f; }
  const float scale = 0.08838834764831845f;  // 128^-0.5

  int ntiles = (q0 + 64) >> 5;
  for (int it = 0; it < ntiles; ++it) {
    int kv0 = it << 5;
    __syncthreads();
    // stage K tile: 32 rows x 128 bf16
#pragma unroll
    for (int i = 0; i < 2; ++i) {
      int c = tid + 256 * i;
      int row = c >> 4, kc = (c & 15) * 8;
      *(short8*)&Ks[row][kc] =
          *(const short8*)(k + ((size_t)(kv0 + row) * NKV + g) * DH + kc);
    }
    // stage V^T tile: 128 d-rows x 32 bf16
#pragma unroll
    for (int i = 0; i < 2; ++i) {
      int c = tid + 256 * i;
      int d = c >> 2, tc = (c & 3) * 8;
      *(short8*)&Vs[d][tc] =
          *(const short8*)(vt + (size_t)(g * DH + d) * TK + kv0 + tc);
    }
    __syncthreads();

    // S = Q K^T : two 16x16 output tiles (kv columns 0..15 and 16..31)
    float4v s0 = {}, s1 = {};
#pragma unroll
    for (int c = 0; c < 4; ++c) {
      short8 b0 = *(const short8*)&Ks[lr][c * 32 + lg * 8];
      short8 b1 = *(const short8*)&Ks[16 + lr][c * 32 + lg * 8];
      s0 = __builtin_amdgcn_mfma_f32_16x16x32_bf16(qf[c], b0, s0, 0, 0, 0);
      s1 = __builtin_amdgcn_mfma_f32_16x16x32_bf16(qf[c], b1, s1, 0, 0, 0);
    }

    // online softmax; acc row i = lg*4 + r, col j = lr
    int qg = q0 + w * 16 + lg * 4;
    float p0[4], p1[4], fac[4];
#pragma unroll
    for (int r = 0; r < 4; ++r) {
      float v0 = s0[r] * scale, v1 = s1[r] * scale;
      if (kv0 + lr > qg + r)      v0 = -1e30f;
      if (kv0 + 16 + lr > qg + r) v1 = -1e30f;
      float mt = fmaxf(v0, v1);
#pragma unroll
      for (int msk = 8; msk >= 1; msk >>= 1) mt = fmaxf(mt, __shfl_xor(mt, msk));
      float mn = fmaxf(m[r], mt);
      float f = __expf(m[r] - mn);
      p0[r] = __expf(v0 - mn);
      p1[r] = __expf(v1 - mn);
      float rs = p0[r] + p1[r];
#pragma unroll
      for (int msk = 8; msk >= 1; msk >>= 1) rs += __shfl_xor(rs, msk);
      l[r] = l[r] * f + rs;
      m[r] = mn;
      fac[r] = f;
    }
#pragma unroll
    for (int ni = 0; ni < 8; ++ni)
#pragma unroll
      for (int r = 0; r < 4; ++r) accO[ni][r] *= fac[r];

    // P -> LDS (per-wave private) to re-layout into A-fragments
#pragma unroll
    for (int r = 0; r < 4; ++r) {
      Ps[w][lg * 4 + r][lr]      = f2bf(p0[r]);
      Ps[w][lg * 4 + r][16 + lr] = f2bf(p1[r]);
    }
    short8 pa = *(const short8*)&Ps[w][lr][lg * 8];
#pragma unroll
    for (int ni = 0; ni < 8; ++ni) {
      short8 bv = *(const short8*)&Vs[ni * 16 + lr][lg * 8];
      accO[ni] = __builtin_amdgcn_mfma_f32_16x16x32_bf16(pa, bv, accO[ni], 0, 0, 0);
    }
  }

  // epilogue: out[i][d], i = lg*4+r, d = ni*16+lr
#pragma unroll
  for (int ni = 0; ni < 8; ++ni)
#pragma unroll
    for (int r = 0; r < 4; ++r) {
      int row = q0 + w * 16 + lg * 4 + r;
      attn[(size_t)row * HIDDEN + h * DH + ni * 16 + lr] = f2bf(accO[ni][r] / l[r]);
    }
}

// ---------------------------------------------------------------------------
extern "C" void kernel_launch(void* const* d_in, const int* in_sizes, int n_in,
                              void* d_out, int out_size, void* d_ws, size_t ws_size,
                              hipStream_t stream) {
  const float* hidden  = (const float*)d_in[0];
  const float* cosb    = (const float*)d_in[1];
  const float* sinb    = (const float*)d_in[2];
  const float* w_qkv   = (const float*)d_in[3];
  const float* w_o     = (const float*)d_in[4];
  const float* k_cache = (const float*)d_in[5];
  const float* v_cache = (const float*)d_in[6];
  const int*   slots   = (const int*)d_in[7];

  float* out = (float*)d_out;                         // [T][HIDDEN]
  float* kco = out + (size_t)TK * HIDDEN;             // [NSLOTS][NKV][DH]
  float* vco = kco + (size_t)NSLOTS * NKV * DH;

  // workspace layout (bytes); total 144 MB
  char* ws = (char*)d_ws;
  const size_t MB = 1024 * 1024;
  unsigned short* hid_bf = (unsigned short*)(ws + 0);         // 16 MB
  unsigned short* wqkvT  = (unsigned short*)(ws + 16 * MB);   // 48 MB [6144][4096]
  unsigned short* woT    = (unsigned short*)(ws + 64 * MB);   // 32 MB [4096][4096]
  unsigned short* qkvb   = (unsigned short*)(ws + 96 * MB);   // 24 MB [T][6144]
  unsigned short* qb     = (unsigned short*)(ws + 120 * MB);  // 16 MB
  unsigned short* kb     = (unsigned short*)(ws + 136 * MB);  //  4 MB
  unsigned short* vtb    = (unsigned short*)(ws + 140 * MB);  //  4 MB
  unsigned short* attnb  = hid_bf;  // reuse: hidden_bf16 dead after QKV GEMM

  // 1) convert inputs to bf16 (+ transpose weights to [N][K])
  convert_f32_bf16<<<2048, 256, 0, stream>>>(hidden, hid_bf, TK * HIDDEN / 4);
  transpose_convert<<<dim3(NQKVC / 64, HIDDEN / 64), 256, 0, stream>>>(
      w_qkv, wqkvT, HIDDEN, NQKVC);
  transpose_convert<<<dim3(HIDDEN / 64, HIDDEN / 64), 256, 0, stream>>>(
      w_o, woT, HIDDEN, HIDDEN);

  // 2) QKV GEMM: [2048][4096] x [4096][6144] -> bf16 [2048][6144]
  gemm_bt<unsigned short><<<dim3(NQKVC / 128, TK / 128), 256, 0, stream>>>(
      hid_bf, wqkvT, qkvb, TK, NQKVC, HIDDEN);

  // 3) cache passthrough copies (d_out is re-poisoned each call)
  hipMemcpyAsync(kco, k_cache, (size_t)NSLOTS * NKV * DH * 4,
                 hipMemcpyDeviceToDevice, stream);
  hipMemcpyAsync(vco, v_cache, (size_t)NSLOTS * NKV * DH * 4,
                 hipMemcpyDeviceToDevice, stream);

  // 4) RoPE + scatter + layout
  rope_scatter<<<TK, 256, 0, stream>>>(qkvb, cosb, sinb, slots,
                                       qb, kb, vtb, kco, vco);

  // 5) flash attention
  attn_kernel<<<dim3(TK / 64, NHEAD), 256, 0, stream>>>(qb, kb, vtb, attnb);

  // 6) output GEMM: [2048][4096] x [4096][4096] -> fp32 d_out
  gemm_bt<float><<<dim3(HIDDEN / 128, TK / 128), 256, 0, stream>>>(
      attnb, woT, out, TK, HIDDEN, HIDDEN);
}

// Round 4
// 715.288 us; speedup vs baseline: 1.1055x; 1.1055x over previous
//
#include <hip/hip_runtime.h>
#include <stdint.h>
#include <stddef.h>
#include <type_traits>

// Problem constants (DeepseekV2Attention_15882789061247)
#define TK      2048   // tokens (B*S)
#define HIDDEN  4096   // H*D
#define NHEAD   32
#define NKV     8
#define DH      128
#define NQKVC   6144   // H*D + 2*KVH*D
#define NSLOTS  4096
#define GROUPS  4      // H / KVH

typedef __attribute__((ext_vector_type(8))) short  short8;
typedef __attribute__((ext_vector_type(4))) short  short4v;
typedef __attribute__((ext_vector_type(4))) float  float4v;

__device__ __forceinline__ unsigned short f2bf(float f) {
  union { float f; unsigned u; } v; v.f = f;
  return (unsigned short)((v.u + 0x7FFFu + ((v.u >> 16) & 1u)) >> 16); // RNE
}
__device__ __forceinline__ float bf2f(unsigned short b) {
  union { unsigned u; float f; } v; v.u = ((unsigned)b) << 16;
  return v.f;
}

// async global->LDS, 16B per lane. dst must be wave-uniform; HW adds lane*16.
__device__ __forceinline__ void gload_lds16(const unsigned short* g, unsigned short* l) {
  __builtin_amdgcn_global_load_lds(
      (const __attribute__((address_space(1))) void*)g,
      (__attribute__((address_space(3))) void*)l, 16, 0, 0);
}

// ---------------- fp32 -> bf16 elementwise convert (vectorized) -------------
__global__ __launch_bounds__(256) void convert_f32_bf16(
    const float* __restrict__ src, unsigned short* __restrict__ dst, int n4) {
  int i = blockIdx.x * blockDim.x + threadIdx.x;
  int stride = gridDim.x * blockDim.x;
  for (; i < n4; i += stride) {
    float4v v = *(const float4v*)(src + (size_t)i * 4);
    short4v o;
#pragma unroll
    for (int j = 0; j < 4; ++j) o[j] = (short)f2bf(v[j]);
    *(short4v*)(dst + (size_t)i * 4) = o;
  }
}

// ---------------- fp32 [K][N] -> bf16 [N][K] tiled transpose ----------------
__global__ __launch_bounds__(256) void transpose_convert(
    const float* __restrict__ src, unsigned short* __restrict__ dst,
    int K, int N) {
  __shared__ float tile[64][65];
  int k0 = blockIdx.y * 64, n0 = blockIdx.x * 64;
  int tc = threadIdx.x & 63, tr = threadIdx.x >> 6;  // tr in 0..3
#pragma unroll
  for (int i = 0; i < 16; ++i) {
    int r = tr + 4 * i;
    tile[r][tc] = src[(size_t)(k0 + r) * N + n0 + tc];
  }
  __syncthreads();
#pragma unroll
  for (int i = 0; i < 16; ++i) {
    int r = tr + 4 * i;
    dst[(size_t)(n0 + r) * K + k0 + tc] = f2bf(tile[tc][r]);
  }
}

// ---- bf16 [T][6144] (v slice) -> bf16 [1024][T] tiled transpose ------------
__global__ __launch_bounds__(256) void v_transpose(
    const unsigned short* __restrict__ qkv, unsigned short* __restrict__ vt) {
  __shared__ unsigned short tile[64][72];
  int t0 = blockIdx.x * 64, e0 = blockIdx.y * 64;
  int tid = threadIdx.x;
  int lrow = tid >> 4, lcol = (tid & 15) * 4;
#pragma unroll
  for (int i = 0; i < 4; ++i) {
    int r = i * 16 + lrow;   // token row
    *(short4v*)&tile[r][lcol] =
        *(const short4v*)&qkv[(size_t)(t0 + r) * NQKVC + 5120 + e0 + lcol];
  }
  __syncthreads();
  int tc = tid & 63, tr = tid >> 6;
#pragma unroll
  for (int i = 0; i < 16; ++i) {
    int e = tr + 4 * i;
    vt[(size_t)(e0 + e) * TK + t0 + tc] = tile[tc][e];
  }
}

// ---------------- bf16 GEMM: C[M][N] = A[M][K] * BT[N][K]^T -----------------
// m97 structure: 128x128 tile, BK=64, 4 waves (2x2), linear LDS,
// global_load_lds width=16 staging, single-buffered.
template <typename OutT>
__global__ __launch_bounds__(256) void gemm_bt(
    const unsigned short* __restrict__ A,   // [M][K] bf16
    const unsigned short* __restrict__ BT,  // [N][K] bf16
    OutT* __restrict__ C,                   // [M][N]
    int M, int N, int K) {
  __shared__ unsigned short As[128][64];
  __shared__ unsigned short Bs[128][64];
  int m0 = blockIdx.y * 128, n0 = blockIdx.x * 128;
  int tid = threadIdx.x;
  int lane = tid & 63, w = tid >> 6;
  int wr = (w >> 1) * 64, wc = (w & 1) * 64;   // wave's 64x64 sub-tile
  int lr = lane & 15, lk = (lane >> 4) * 8;    // fragment row / k-group
  int srow = lane >> 3, scol = (lane & 7) * 8; // staging lane decomposition

  float4v acc[4][4] = {};

  for (int k0 = 0; k0 < K; k0 += 64) {
    // stage A-tile and BT-tile: each 128 rows x 64 bf16 (16KB), 4x1KB per wave
#pragma unroll
    for (int i = 0; i < 4; ++i) {
      int row = w * 32 + i * 8;
      gload_lds16(A + (size_t)(m0 + row + srow) * K + k0 + scol, &As[row][0]);
      gload_lds16(BT + (size_t)(n0 + row + srow) * K + k0 + scol, &Bs[row][0]);
    }
    __syncthreads();   // drains vmcnt -> tiles visible
#pragma unroll
    for (int kk = 0; kk < 64; kk += 32) {
      short8 a[4], b[4];
#pragma unroll
      for (int mi = 0; mi < 4; ++mi) a[mi] = *(const short8*)&As[wr + mi * 16 + lr][kk + lk];
#pragma unroll
      for (int ni = 0; ni < 4; ++ni) b[ni] = *(const short8*)&Bs[wc + ni * 16 + lr][kk + lk];
#pragma unroll
      for (int mi = 0; mi < 4; ++mi)
#pragma unroll
        for (int ni = 0; ni < 4; ++ni)
          acc[mi][ni] = __builtin_amdgcn_mfma_f32_16x16x32_bf16(a[mi], b[ni], acc[mi][ni], 0, 0, 0);
    }
    __syncthreads();
  }

  // epilogue: C/D layout col = lane&15, row = (lane>>4)*4 + r  [m89-verified]
  int orow = (lane >> 4) * 4;
#pragma unroll
  for (int mi = 0; mi < 4; ++mi)
#pragma unroll
    for (int ni = 0; ni < 4; ++ni)
#pragma unroll
      for (int r = 0; r < 4; ++r) {
        float v = acc[mi][ni][r];
        size_t idx = (size_t)(m0 + wr + mi * 16 + orow + r) * N + n0 + wc + ni * 16 + lr;
        if constexpr (std::is_same<OutT, unsigned short>::value)
          C[idx] = f2bf(v);
        else
          C[idx] = v;
      }
}

// ---------------- RoPE + KV-cache scatter + layout producers ----------------
__global__ __launch_bounds__(256) void rope_scatter(
    const unsigned short* __restrict__ qkv,   // [T][6144]
    const float* __restrict__ cosb,           // [T][64]
    const float* __restrict__ sinb,           // [T][64]
    const int* __restrict__ slots,
    unsigned short* __restrict__ qout,        // [T][4096]
    unsigned short* __restrict__ kout,        // [T][1024]
    float* __restrict__ kcache,               // [NSLOTS][1024] (output)
    float* __restrict__ vcache) {             // [NSLOTS][1024] (output)
  int t = blockIdx.x;
  int tid = threadIdx.x;
  int slot = slots[t];
  const unsigned short* row = qkv + (size_t)t * NQKVC;

#pragma unroll
  for (int i = 0; i < 8; ++i) {
    int p = tid + 256 * i;
    int h = p >> 6, d = p & 63;
    float x1 = bf2f(row[h * 128 + d]);
    float x2 = bf2f(row[h * 128 + d + 64]);
    float c = cosb[t * 64 + d], s = sinb[t * 64 + d];
    qout[(size_t)t * HIDDEN + h * 128 + d]      = f2bf(x1 * c - x2 * s);
    qout[(size_t)t * HIDDEN + h * 128 + d + 64] = f2bf(x2 * c + x1 * s);
  }
#pragma unroll
  for (int i = 0; i < 2; ++i) {
    int p = tid + 256 * i;
    int kh = p >> 6, d = p & 63;
    float x1 = bf2f(row[4096 + kh * 128 + d]);
    float x2 = bf2f(row[4096 + kh * 128 + d + 64]);
    float c = cosb[t * 64 + d], s = sinb[t * 64 + d];
    float o1 = x1 * c - x2 * s, o2 = x2 * c + x1 * s;
    kout[t * 1024 + kh * 128 + d]      = f2bf(o1);
    kout[t * 1024 + kh * 128 + d + 64] = f2bf(o2);
    kcache[(size_t)slot * 1024 + kh * 128 + d]      = o1;
    kcache[(size_t)slot * 1024 + kh * 128 + d + 64] = o2;
  }
#pragma unroll
  for (int i = 0; i < 4; ++i) {
    int e = tid + 256 * i;
    vcache[(size_t)slot * 1024 + e] = bf2f(row[5120 + e]);
  }
}

// ---------------- flash attention (causal, GQA) -----------------------------
// grid (16, 32); block = 4 waves. Each block processes q-tiles (31-bx) and bx
// (64 rows each) -> uniform 68 KV-tile iterations per block.
// K/V staged via global_load_lds with pre-swizzled source; XOR-swizzled reads.
// Swizzle invariant (rule 21): LDS[row][chunk] = global[row][chunk ^ (row&7)]
// for K (chunk=8 bf16), and chunk ^ (row&3) for V. The staging source chunk
// MUST use the full LDS row parity, incl. the per-call base row (r3 bugfix).
__global__ __launch_bounds__(256) void attn_kernel(
    const unsigned short* __restrict__ q,    // [T][H][D]
    const unsigned short* __restrict__ k,    // [T][KVH][D]
    const unsigned short* __restrict__ vt,   // [KVH*D][T]
    unsigned short* __restrict__ attn) {     // [T][H*D]
  __shared__ unsigned short Ks[2][32][128];  // linear, swizzle chunk^=(row&7)
  __shared__ unsigned short Vs[2][128][32];  // linear, swizzle chunk^=(row&3)
  __shared__ unsigned short Ps[4][16][40];   // per-wave P relayout buffer

  const int h = blockIdx.y;
  const int g = h >> 2;                      // kv head
  const int tid = threadIdx.x, lane = tid & 63, w = tid >> 6;
  const int lr = lane & 15, lg = lane >> 4;
  const float scale = 0.08838834764831845f;  // 128^-0.5

  // staging lane decompositions (dst is linear; source pre-swizzled)
  const int ksrow = lane >> 4;   // row offset within one 4-row K stage call
  const int vsrow = lane >> 2;   // row offset within one 16-row V stage call
  const int vscc = ((lane & 3) ^ (vsrow & 3)) * 8;  // (vrow%16==0 -> row&3==vsrow&3)

  for (int half = 0; half < 2; ++half) {
    const int q0 = (half == 0 ? (31 - (int)blockIdx.x) : (int)blockIdx.x) * 64;
    const int nt = (q0 >> 5) + 2;

    // Q fragments for this q-tile
    short8 qf[4];
    int qrow = q0 + w * 16 + lr;
#pragma unroll
    for (int c = 0; c < 4; ++c)
      qf[c] = *(const short8*)(q + (size_t)qrow * HIDDEN + h * DH + c * 32 + lg * 8);

    float4v accO[8] = {};
    float m[4], l[4];
#pragma unroll
    for (int r = 0; r < 4; ++r) { m[r] = -1e30f; l[r] = 0.f; }

    // prologue stage tile 0 into buf 0
#pragma unroll
    for (int i = 0; i < 2; ++i) {
      int krow = w * 8 + i * 4;
      int kcc = ((lane & 15) ^ ((krow + ksrow) & 7)) * 8;   // full row parity!
      gload_lds16(k + ((size_t)(krow + ksrow) * NKV + g) * DH + kcc, &Ks[0][krow][0]);
      int vrow = w * 32 + i * 16;
      gload_lds16(vt + (size_t)(g * DH + vrow + vsrow) * TK + vscc, &Vs[0][vrow][0]);
    }

    int cur = 0;
    for (int it = 0; it < nt; ++it) {
      int kv0 = it << 5;
      __syncthreads();  // waits vmcnt(0): buf[cur] staged; prev compute done
      if (it + 1 < nt) {
        int kv1 = kv0 + 32;
#pragma unroll
        for (int i = 0; i < 2; ++i) {
          int krow = w * 8 + i * 4;
          int kcc = ((lane & 15) ^ ((krow + ksrow) & 7)) * 8;
          gload_lds16(k + ((size_t)(kv1 + krow + ksrow) * NKV + g) * DH + kcc,
                      &Ks[cur ^ 1][krow][0]);
          int vrow = w * 32 + i * 16;
          gload_lds16(vt + (size_t)(g * DH + vrow + vsrow) * TK + kv1 + vscc,
                      &Vs[cur ^ 1][vrow][0]);
        }
      }

      // S = Q K^T : rows lr and 16+lr of K-tile; swizzled column chunks
      float4v s0 = {}, s1 = {};
#pragma unroll
      for (int c = 0; c < 4; ++c) {
        int cc = ((c * 4 + lg) ^ (lr & 7)) * 8;   // (16+lr)&7 == lr&7
        short8 b0 = *(const short8*)&Ks[cur][lr][cc];
        short8 b1 = *(const short8*)&Ks[cur][16 + lr][cc];
        s0 = __builtin_amdgcn_mfma_f32_16x16x32_bf16(qf[c], b0, s0, 0, 0, 0);
        s1 = __builtin_amdgcn_mfma_f32_16x16x32_bf16(qf[c], b1, s1, 0, 0, 0);
      }

      // online softmax; acc row i = lg*4 + r, col j = lr
      int qg = q0 + w * 16 + lg * 4;
      bool domask = (kv0 + 31 > q0 + w * 16);
      float p0[4], p1[4], fac[4];
#pragma unroll
      for (int r = 0; r < 4; ++r) {
        float v0 = s0[r] * scale, v1 = s1[r] * scale;
        if (domask) {
          if (kv0 + lr > qg + r)      v0 = -1e30f;
          if (kv0 + 16 + lr > qg + r) v1 = -1e30f;
        }
        float mt = fmaxf(v0, v1);
#pragma unroll
        for (int msk = 8; msk >= 1; msk >>= 1) mt = fmaxf(mt, __shfl_xor(mt, msk));
        float mn = fmaxf(m[r], mt);
        float f = __expf(m[r] - mn);
        p0[r] = __expf(v0 - mn);
        p1[r] = __expf(v1 - mn);
        float rs = p0[r] + p1[r];
#pragma unroll
        for (int msk = 8; msk >= 1; msk >>= 1) rs += __shfl_xor(rs, msk);
        l[r] = l[r] * f + rs;
        m[r] = mn;
        fac[r] = f;
      }
#pragma unroll
      for (int ni = 0; ni < 8; ++ni)
#pragma unroll
        for (int r = 0; r < 4; ++r) accO[ni][r] *= fac[r];

      // P -> per-wave LDS to re-layout into A-fragments
#pragma unroll
      for (int r = 0; r < 4; ++r) {
        Ps[w][lg * 4 + r][lr]      = f2bf(p0[r]);
        Ps[w][lg * 4 + r][16 + lr] = f2bf(p1[r]);
      }
      short8 pa = *(const short8*)&Ps[w][lr][lg * 8];
      int vcc = (lg ^ (lr & 3)) * 8;   // (ni*16+lr)&3 == lr&3
#pragma unroll
      for (int ni = 0; ni < 8; ++ni) {
        short8 bv = *(const short8*)&Vs[cur][ni * 16 + lr][vcc];
        accO[ni] = __builtin_amdgcn_mfma_f32_16x16x32_bf16(pa, bv, accO[ni], 0, 0, 0);
      }
      cur ^= 1;
    }
    __syncthreads();  // all LDS reads done before next half re-stages

    // epilogue: out[i][d], i = lg*4+r, d = ni*16+lr
#pragma unroll
    for (int ni = 0; ni < 8; ++ni)
#pragma unroll
      for (int r = 0; r < 4; ++r) {
        int row = q0 + w * 16 + lg * 4 + r;
        attn[(size_t)row * HIDDEN + h * DH + ni * 16 + lr] = f2bf(accO[ni][r] / l[r]);
      }
  }
}

// ---------------------------------------------------------------------------
extern "C" void kernel_launch(void* const* d_in, const int* in_sizes, int n_in,
                              void* d_out, int out_size, void* d_ws, size_t ws_size,
                              hipStream_t stream) {
  const float* hidden  = (const float*)d_in[0];
  const float* cosb    = (const float*)d_in[1];
  const float* sinb    = (const float*)d_in[2];
  const float* w_qkv   = (const float*)d_in[3];
  const float* w_o     = (const float*)d_in[4];
  const float* k_cache = (const float*)d_in[5];
  const float* v_cache = (const float*)d_in[6];
  const int*   slots   = (const int*)d_in[7];

  float* out = (float*)d_out;                         // [T][HIDDEN]
  float* kco = out + (size_t)TK * HIDDEN;             // [NSLOTS][NKV][DH]
  float* vco = kco + (size_t)NSLOTS * NKV * DH;

  // workspace layout (bytes); total 144 MB
  char* ws = (char*)d_ws;
  const size_t MB = 1024 * 1024;
  unsigned short* hid_bf = (unsigned short*)(ws + 0);         // 16 MB
  unsigned short* wqkvT  = (unsigned short*)(ws + 16 * MB);   // 48 MB [6144][4096]
  unsigned short* woT    = (unsigned short*)(ws + 64 * MB);   // 32 MB [4096][4096]
  unsigned short* qkvb   = (unsigned short*)(ws + 96 * MB);   // 24 MB [T][6144]
  unsigned short* qb     = (unsigned short*)(ws + 120 * MB);  // 16 MB
  unsigned short* kb     = (unsigned short*)(ws + 136 * MB);  //  4 MB
  unsigned short* vtb    = (unsigned short*)(ws + 140 * MB);  //  4 MB
  unsigned short* attnb  = hid_bf;  // reuse: hidden_bf16 dead after QKV GEMM

  // 1) convert inputs to bf16 (+ transpose weights to [N][K])
  convert_f32_bf16<<<2048, 256, 0, stream>>>(hidden, hid_bf, TK * HIDDEN / 4);
  transpose_convert<<<dim3(NQKVC / 64, HIDDEN / 64), 256, 0, stream>>>(
      w_qkv, wqkvT, HIDDEN, NQKVC);
  transpose_convert<<<dim3(HIDDEN / 64, HIDDEN / 64), 256, 0, stream>>>(
      w_o, woT, HIDDEN, HIDDEN);

  // 2) QKV GEMM: [2048][4096] x [4096][6144] -> bf16 [2048][6144]
  gemm_bt<unsigned short><<<dim3(NQKVC / 128, TK / 128), 256, 0, stream>>>(
      hid_bf, wqkvT, qkvb, TK, NQKVC, HIDDEN);

  // 3) cache passthrough copies (d_out is re-poisoned each call)
  hipMemcpyAsync(kco, k_cache, (size_t)NSLOTS * NKV * DH * 4,
                 hipMemcpyDeviceToDevice, stream);
  hipMemcpyAsync(vco, v_cache, (size_t)NSLOTS * NKV * DH * 4,
                 hipMemcpyDeviceToDevice, stream);

  // 4) RoPE + cache scatter; V transpose for PV B-operand layout
  rope_scatter<<<TK, 256, 0, stream>>>(qkvb, cosb, sinb, slots,
                                       qb, kb, kco, vco);
  v_transpose<<<dim3(TK / 64, 16), 256, 0, stream>>>(qkvb, vtb);

  // 5) flash attention (paired q-tiles for causal load balance)
  attn_kernel<<<dim3(16, NHEAD), 256, 0, stream>>>(qb, kb, vtb, attnb);

  // 6) output GEMM: [2048][4096] x [4096][4096] -> fp32 d_out
  gemm_bt<float><<<dim3(HIDDEN / 128, TK / 128), 256, 0, stream>>>(
      attnb, woT, out, TK, HIDDEN, HIDDEN);
}

// Round 5
// 616.733 us; speedup vs baseline: 1.2821x; 1.1598x over previous
//
#include <hip/hip_runtime.h>
#include <stdint.h>
#include <stddef.h>
#include <type_traits>

// Problem constants (DeepseekV2Attention_15882789061247)
#define TK      2048   // tokens (B*S)
#define HIDDEN  4096   // H*D
#define NHEAD   32
#define NKV     8
#define DH      128
#define NQKVC   6144   // H*D + 2*KVH*D
#define NSLOTS  4096
#define GROUPS  4      // H / KVH

typedef __attribute__((ext_vector_type(8))) short  short8;
typedef __attribute__((ext_vector_type(4))) short  short4v;
typedef __attribute__((ext_vector_type(4))) float  float4v;

__device__ __forceinline__ unsigned short f2bf(float f) {
  union { float f; unsigned u; } v; v.f = f;
  return (unsigned short)((v.u + 0x7FFFu + ((v.u >> 16) & 1u)) >> 16); // RNE
}
__device__ __forceinline__ float bf2f(unsigned short b) {
  union { unsigned u; float f; } v; v.u = ((unsigned)b) << 16;
  return v.f;
}

// async global->LDS, 16B per lane. dst must be wave-uniform; HW adds lane*16.
__device__ __forceinline__ void gload_lds16(const unsigned short* g, unsigned short* l) {
  __builtin_amdgcn_global_load_lds(
      (const __attribute__((address_space(1))) void*)g,
      (__attribute__((address_space(3))) void*)l, 16, 0, 0);
}

// ---------------- fp32 -> bf16 elementwise convert (vectorized) -------------
__global__ __launch_bounds__(256) void convert_f32_bf16(
    const float* __restrict__ src, unsigned short* __restrict__ dst, int n4) {
  int i = blockIdx.x * blockDim.x + threadIdx.x;
  int stride = gridDim.x * blockDim.x;
  for (; i < n4; i += stride) {
    float4v v = *(const float4v*)(src + (size_t)i * 4);
    short4v o;
#pragma unroll
    for (int j = 0; j < 4; ++j) o[j] = (short)f2bf(v[j]);
    *(short4v*)(dst + (size_t)i * 4) = o;
  }
}

// ---------------- fp32 [K][N] -> bf16 [N][K] tiled transpose ----------------
__global__ __launch_bounds__(256) void transpose_convert(
    const float* __restrict__ src, unsigned short* __restrict__ dst,
    int K, int N) {
  __shared__ float tile[64][65];
  int k0 = blockIdx.y * 64, n0 = blockIdx.x * 64;
  int tc = threadIdx.x & 63, tr = threadIdx.x >> 6;  // tr in 0..3
#pragma unroll
  for (int i = 0; i < 16; ++i) {
    int r = tr + 4 * i;
    tile[r][tc] = src[(size_t)(k0 + r) * N + n0 + tc];
  }
  __syncthreads();
#pragma unroll
  for (int i = 0; i < 16; ++i) {
    int r = tr + 4 * i;
    dst[(size_t)(n0 + r) * K + k0 + tc] = f2bf(tile[tc][r]);
  }
}

// ---- bf16 [T][6144] (v slice) -> bf16 [1024][T] tiled transpose ------------
__global__ __launch_bounds__(256) void v_transpose(
    const unsigned short* __restrict__ qkv, unsigned short* __restrict__ vt) {
  __shared__ unsigned short tile[64][72];
  int t0 = blockIdx.x * 64, e0 = blockIdx.y * 64;
  int tid = threadIdx.x;
  int lrow = tid >> 4, lcol = (tid & 15) * 4;
#pragma unroll
  for (int i = 0; i < 4; ++i) {
    int r = i * 16 + lrow;   // token row
    *(short4v*)&tile[r][lcol] =
        *(const short4v*)&qkv[(size_t)(t0 + r) * NQKVC + 5120 + e0 + lcol];
  }
  __syncthreads();
  int tc = tid & 63, tr = tid >> 6;
#pragma unroll
  for (int i = 0; i < 16; ++i) {
    int e = tr + 4 * i;
    vt[(size_t)(e0 + e) * TK + t0 + tc] = tile[tc][e];
  }
}

// ---------------- bf16 GEMM: C[M][N] = A[M][K] * BT[N][K]^T -----------------
// m97 structure: 128x128 tile, BK=64, 4 waves (2x2), global_load_lds staging.
// r4: LDS XOR-swizzle (rule 21, both-sides): LDS[row][cp] = G[row][cp^(row&7)]
// (cp = 16B chunk 0..7). Kills the 16-way stride-128B ds_read_b128 conflict
// (SQ_LDS_BANK_CONFLICT 3.78e7/dispatch -> post-swizzle 8 lanes per 4-bank
// group = 2/bank = free). Staging dest stays linear; source pre-swizzled.
template <typename OutT>
__global__ __launch_bounds__(256) void gemm_bt(
    const unsigned short* __restrict__ A,   // [M][K] bf16
    const unsigned short* __restrict__ BT,  // [N][K] bf16
    OutT* __restrict__ C,                   // [M][N]
    int M, int N, int K) {
  __shared__ unsigned short As[128][64];
  __shared__ unsigned short Bs[128][64];
  int m0 = blockIdx.y * 128, n0 = blockIdx.x * 128;
  int tid = threadIdx.x;
  int lane = tid & 63, w = tid >> 6;
  int wr = (w >> 1) * 64, wc = (w & 1) * 64;   // wave's 64x64 sub-tile
  int lr = lane & 15, lg = lane >> 4;          // fragment row / k-group
  int srow = lane >> 3;                        // staging row within 8-row call
  int scol = ((lane & 7) ^ (srow & 7)) * 8;    // inverse-swizzled source chunk
                                               // (row base % 8 == 0 -> row&7 == srow&7)

  float4v acc[4][4] = {};

  for (int k0 = 0; k0 < K; k0 += 64) {
    // stage A-tile and BT-tile: each 128 rows x 64 bf16 (16KB), 4x1KB per wave
#pragma unroll
    for (int i = 0; i < 4; ++i) {
      int row = w * 32 + i * 8;
      gload_lds16(A + (size_t)(m0 + row + srow) * K + k0 + scol, &As[row][0]);
      gload_lds16(BT + (size_t)(n0 + row + srow) * K + k0 + scol, &Bs[row][0]);
    }
    __syncthreads();   // drains vmcnt -> tiles visible
#pragma unroll
    for (int kk = 0; kk < 64; kk += 32) {
      // swizzled read chunk: want G-chunk (kk/8+lg) of row; row&7 == lr&7
      int cc = (((kk >> 3) + lg) ^ (lr & 7)) * 8;
      short8 a[4], b[4];
#pragma unroll
      for (int mi = 0; mi < 4; ++mi) a[mi] = *(const short8*)&As[wr + mi * 16 + lr][cc];
#pragma unroll
      for (int ni = 0; ni < 4; ++ni) b[ni] = *(const short8*)&Bs[wc + ni * 16 + lr][cc];
#pragma unroll
      for (int mi = 0; mi < 4; ++mi)
#pragma unroll
        for (int ni = 0; ni < 4; ++ni)
          acc[mi][ni] = __builtin_amdgcn_mfma_f32_16x16x32_bf16(a[mi], b[ni], acc[mi][ni], 0, 0, 0);
    }
    __syncthreads();
  }

  // epilogue: C/D layout col = lane&15, row = (lane>>4)*4 + r  [m89-verified]
  int orow = (lane >> 4) * 4;
#pragma unroll
  for (int mi = 0; mi < 4; ++mi)
#pragma unroll
    for (int ni = 0; ni < 4; ++ni)
#pragma unroll
      for (int r = 0; r < 4; ++r) {
        float v = acc[mi][ni][r];
        size_t idx = (size_t)(m0 + wr + mi * 16 + orow + r) * N + n0 + wc + ni * 16 + lr;
        if constexpr (std::is_same<OutT, unsigned short>::value)
          C[idx] = f2bf(v);
        else
          C[idx] = v;
      }
}

// ---------------- RoPE + KV-cache scatter + layout producers ----------------
__global__ __launch_bounds__(256) void rope_scatter(
    const unsigned short* __restrict__ qkv,   // [T][6144]
    const float* __restrict__ cosb,           // [T][64]
    const float* __restrict__ sinb,           // [T][64]
    const int* __restrict__ slots,
    unsigned short* __restrict__ qout,        // [T][4096]
    unsigned short* __restrict__ kout,        // [T][1024]
    float* __restrict__ kcache,               // [NSLOTS][1024] (output)
    float* __restrict__ vcache) {             // [NSLOTS][1024] (output)
  int t = blockIdx.x;
  int tid = threadIdx.x;
  int slot = slots[t];
  const unsigned short* row = qkv + (size_t)t * NQKVC;

#pragma unroll
  for (int i = 0; i < 8; ++i) {
    int p = tid + 256 * i;
    int h = p >> 6, d = p & 63;
    float x1 = bf2f(row[h * 128 + d]);
    float x2 = bf2f(row[h * 128 + d + 64]);
    float c = cosb[t * 64 + d], s = sinb[t * 64 + d];
    qout[(size_t)t * HIDDEN + h * 128 + d]      = f2bf(x1 * c - x2 * s);
    qout[(size_t)t * HIDDEN + h * 128 + d + 64] = f2bf(x2 * c + x1 * s);
  }
#pragma unroll
  for (int i = 0; i < 2; ++i) {
    int p = tid + 256 * i;
    int kh = p >> 6, d = p & 63;
    float x1 = bf2f(row[4096 + kh * 128 + d]);
    float x2 = bf2f(row[4096 + kh * 128 + d + 64]);
    float c = cosb[t * 64 + d], s = sinb[t * 64 + d];
    float o1 = x1 * c - x2 * s, o2 = x2 * c + x1 * s;
    kout[t * 1024 + kh * 128 + d]      = f2bf(o1);
    kout[t * 1024 + kh * 128 + d + 64] = f2bf(o2);
    kcache[(size_t)slot * 1024 + kh * 128 + d]      = o1;
    kcache[(size_t)slot * 1024 + kh * 128 + d + 64] = o2;
  }
#pragma unroll
  for (int i = 0; i < 4; ++i) {
    int e = tid + 256 * i;
    vcache[(size_t)slot * 1024 + e] = bf2f(row[5120 + e]);
  }
}

// ---------------- flash attention (causal, GQA) -----------------------------
// grid (16, 32); block = 4 waves. Each block processes q-tiles (31-bx) and bx
// (64 rows each) -> uniform 68 KV-tile iterations per block.
// K/V staged via global_load_lds with pre-swizzled source; XOR-swizzled reads.
// Swizzle invariant (rule 21): LDS[row][chunk] = global[row][chunk ^ (row&7)]
// for K (chunk=8 bf16), and chunk ^ (row&3) for V. The staging source chunk
// MUST use the full LDS row parity, incl. the per-call base row (r3 bugfix).
__global__ __launch_bounds__(256) void attn_kernel(
    const unsigned short* __restrict__ q,    // [T][H][D]
    const unsigned short* __restrict__ k,    // [T][KVH][D]
    const unsigned short* __restrict__ vt,   // [KVH*D][T]
    unsigned short* __restrict__ attn) {     // [T][H*D]
  __shared__ unsigned short Ks[2][32][128];  // linear, swizzle chunk^=(row&7)
  __shared__ unsigned short Vs[2][128][32];  // linear, swizzle chunk^=(row&3)
  __shared__ unsigned short Ps[4][16][40];   // per-wave P relayout buffer

  const int h = blockIdx.y;
  const int g = h >> 2;                      // kv head
  const int tid = threadIdx.x, lane = tid & 63, w = tid >> 6;
  const int lr = lane & 15, lg = lane >> 4;
  const float scale = 0.08838834764831845f;  // 128^-0.5

  // staging lane decompositions (dst is linear; source pre-swizzled)
  const int ksrow = lane >> 4;   // row offset within one 4-row K stage call
  const int vsrow = lane >> 2;   // row offset within one 16-row V stage call
  const int vscc = ((lane & 3) ^ (vsrow & 3)) * 8;  // (vrow%16==0 -> row&3==vsrow&3)

  for (int half = 0; half < 2; ++half) {
    const int q0 = (half == 0 ? (31 - (int)blockIdx.x) : (int)blockIdx.x) * 64;
    const int nt = (q0 >> 5) + 2;

    // Q fragments for this q-tile
    short8 qf[4];
    int qrow = q0 + w * 16 + lr;
#pragma unroll
    for (int c = 0; c < 4; ++c)
      qf[c] = *(const short8*)(q + (size_t)qrow * HIDDEN + h * DH + c * 32 + lg * 8);

    float4v accO[8] = {};
    float m[4], l[4];
#pragma unroll
    for (int r = 0; r < 4; ++r) { m[r] = -1e30f; l[r] = 0.f; }

    // prologue stage tile 0 into buf 0
#pragma unroll
    for (int i = 0; i < 2; ++i) {
      int krow = w * 8 + i * 4;
      int kcc = ((lane & 15) ^ ((krow + ksrow) & 7)) * 8;   // full row parity!
      gload_lds16(k + ((size_t)(krow + ksrow) * NKV + g) * DH + kcc, &Ks[0][krow][0]);
      int vrow = w * 32 + i * 16;
      gload_lds16(vt + (size_t)(g * DH + vrow + vsrow) * TK + vscc, &Vs[0][vrow][0]);
    }

    int cur = 0;
    for (int it = 0; it < nt; ++it) {
      int kv0 = it << 5;
      __syncthreads();  // waits vmcnt(0): buf[cur] staged; prev compute done
      if (it + 1 < nt) {
        int kv1 = kv0 + 32;
#pragma unroll
        for (int i = 0; i < 2; ++i) {
          int krow = w * 8 + i * 4;
          int kcc = ((lane & 15) ^ ((krow + ksrow) & 7)) * 8;
          gload_lds16(k + ((size_t)(kv1 + krow + ksrow) * NKV + g) * DH + kcc,
                      &Ks[cur ^ 1][krow][0]);
          int vrow = w * 32 + i * 16;
          gload_lds16(vt + (size_t)(g * DH + vrow + vsrow) * TK + kv1 + vscc,
                      &Vs[cur ^ 1][vrow][0]);
        }
      }

      // S = Q K^T : rows lr and 16+lr of K-tile; swizzled column chunks
      float4v s0 = {}, s1 = {};
#pragma unroll
      for (int c = 0; c < 4; ++c) {
        int cc = ((c * 4 + lg) ^ (lr & 7)) * 8;   // (16+lr)&7 == lr&7
        short8 b0 = *(const short8*)&Ks[cur][lr][cc];
        short8 b1 = *(const short8*)&Ks[cur][16 + lr][cc];
        s0 = __builtin_amdgcn_mfma_f32_16x16x32_bf16(qf[c], b0, s0, 0, 0, 0);
        s1 = __builtin_amdgcn_mfma_f32_16x16x32_bf16(qf[c], b1, s1, 0, 0, 0);
      }

      // online softmax; acc row i = lg*4 + r, col j = lr
      int qg = q0 + w * 16 + lg * 4;
      bool domask = (kv0 + 31 > q0 + w * 16);
      float p0[4], p1[4], fac[4];
#pragma unroll
      for (int r = 0; r < 4; ++r) {
        float v0 = s0[r] * scale, v1 = s1[r] * scale;
        if (domask) {
          if (kv0 + lr > qg + r)      v0 = -1e30f;
          if (kv0 + 16 + lr > qg + r) v1 = -1e30f;
        }
        float mt = fmaxf(v0, v1);
#pragma unroll
        for (int msk = 8; msk >= 1; msk >>= 1) mt = fmaxf(mt, __shfl_xor(mt, msk));
        float mn = fmaxf(m[r], mt);
        float f = __expf(m[r] - mn);
        p0[r] = __expf(v0 - mn);
        p1[r] = __expf(v1 - mn);
        float rs = p0[r] + p1[r];
#pragma unroll
        for (int msk = 8; msk >= 1; msk >>= 1) rs += __shfl_xor(rs, msk);
        l[r] = l[r] * f + rs;
        m[r] = mn;
        fac[r] = f;
      }
#pragma unroll
      for (int ni = 0; ni < 8; ++ni)
#pragma unroll
        for (int r = 0; r < 4; ++r) accO[ni][r] *= fac[r];

      // P -> per-wave LDS to re-layout into A-fragments
#pragma unroll
      for (int r = 0; r < 4; ++r) {
        Ps[w][lg * 4 + r][lr]      = f2bf(p0[r]);
        Ps[w][lg * 4 + r][16 + lr] = f2bf(p1[r]);
      }
      short8 pa = *(const short8*)&Ps[w][lr][lg * 8];
      int vcc = (lg ^ (lr & 3)) * 8;   // (ni*16+lr)&3 == lr&3
#pragma unroll
      for (int ni = 0; ni < 8; ++ni) {
        short8 bv = *(const short8*)&Vs[cur][ni * 16 + lr][vcc];
        accO[ni] = __builtin_amdgcn_mfma_f32_16x16x32_bf16(pa, bv, accO[ni], 0, 0, 0);
      }
      cur ^= 1;
    }
    __syncthreads();  // all LDS reads done before next half re-stages

    // epilogue: out[i][d], i = lg*4+r, d = ni*16+lr
#pragma unroll
    for (int ni = 0; ni < 8; ++ni)
#pragma unroll
      for (int r = 0; r < 4; ++r) {
        int row = q0 + w * 16 + lg * 4 + r;
        attn[(size_t)row * HIDDEN + h * DH + ni * 16 + lr] = f2bf(accO[ni][r] / l[r]);
      }
  }
}

// ---------------------------------------------------------------------------
extern "C" void kernel_launch(void* const* d_in, const int* in_sizes, int n_in,
                              void* d_out, int out_size, void* d_ws, size_t ws_size,
                              hipStream_t stream) {
  const float* hidden  = (const float*)d_in[0];
  const float* cosb    = (const float*)d_in[1];
  const float* sinb    = (const float*)d_in[2];
  const float* w_qkv   = (const float*)d_in[3];
  const float* w_o     = (const float*)d_in[4];
  const float* k_cache = (const float*)d_in[5];
  const float* v_cache = (const float*)d_in[6];
  const int*   slots   = (const int*)d_in[7];

  float* out = (float*)d_out;                         // [T][HIDDEN]
  float* kco = out + (size_t)TK * HIDDEN;             // [NSLOTS][NKV][DH]
  float* vco = kco + (size_t)NSLOTS * NKV * DH;

  // workspace layout (bytes); total 144 MB
  char* ws = (char*)d_ws;
  const size_t MB = 1024 * 1024;
  unsigned short* hid_bf = (unsigned short*)(ws + 0);         // 16 MB
  unsigned short* wqkvT  = (unsigned short*)(ws + 16 * MB);   // 48 MB [6144][4096]
  unsigned short* woT    = (unsigned short*)(ws + 64 * MB);   // 32 MB [4096][4096]
  unsigned short* qkvb   = (unsigned short*)(ws + 96 * MB);   // 24 MB [T][6144]
  unsigned short* qb     = (unsigned short*)(ws + 120 * MB);  // 16 MB
  unsigned short* kb     = (unsigned short*)(ws + 136 * MB);  //  4 MB
  unsigned short* vtb    = (unsigned short*)(ws + 140 * MB);  //  4 MB
  unsigned short* attnb  = hid_bf;  // reuse: hidden_bf16 dead after QKV GEMM

  // 1) convert inputs to bf16 (+ transpose weights to [N][K])
  convert_f32_bf16<<<2048, 256, 0, stream>>>(hidden, hid_bf, TK * HIDDEN / 4);
  transpose_convert<<<dim3(NQKVC / 64, HIDDEN / 64), 256, 0, stream>>>(
      w_qkv, wqkvT, HIDDEN, NQKVC);
  transpose_convert<<<dim3(HIDDEN / 64, HIDDEN / 64), 256, 0, stream>>>(
      w_o, woT, HIDDEN, HIDDEN);

  // 2) QKV GEMM: [2048][4096] x [4096][6144] -> bf16 [2048][6144]
  gemm_bt<unsigned short><<<dim3(NQKVC / 128, TK / 128), 256, 0, stream>>>(
      hid_bf, wqkvT, qkvb, TK, NQKVC, HIDDEN);

  // 3) cache passthrough copies (d_out is re-poisoned each call)
  hipMemcpyAsync(kco, k_cache, (size_t)NSLOTS * NKV * DH * 4,
                 hipMemcpyDeviceToDevice, stream);
  hipMemcpyAsync(vco, v_cache, (size_t)NSLOTS * NKV * DH * 4,
                 hipMemcpyDeviceToDevice, stream);

  // 4) RoPE + cache scatter; V transpose for PV B-operand layout
  rope_scatter<<<TK, 256, 0, stream>>>(qkvb, cosb, sinb, slots,
                                       qb, kb, kco, vco);
  v_transpose<<<dim3(TK / 64, 16), 256, 0, stream>>>(qkvb, vtb);

  // 5) flash attention (paired q-tiles for causal load balance)
  attn_kernel<<<dim3(16, NHEAD), 256, 0, stream>>>(qb, kb, vtb, attnb);

  // 6) output GEMM: [2048][4096] x [4096][4096] -> fp32 d_out
  gemm_bt<float><<<dim3(HIDDEN / 128, TK / 128), 256, 0, stream>>>(
      attnb, woT, out, TK, HIDDEN, HIDDEN);
}

// Round 8
// 603.170 us; speedup vs baseline: 1.3110x; 1.0225x over previous
//
#include <hip/hip_runtime.h>
#include <stdint.h>
#include <stddef.h>
#include <type_traits>

// Problem constants (DeepseekV2Attention_15882789061247)
#define TK      2048   // tokens (B*S)
#define HIDDEN  4096   // H*D
#define NHEAD   32
#define NKV     8
#define DH      128
#define NQKVC   6144   // H*D + 2*KVH*D
#define NSLOTS  4096
#define GROUPS  4      // H / KVH

typedef __attribute__((ext_vector_type(8))) short  short8;
typedef __attribute__((ext_vector_type(4))) short  short4v;
typedef __attribute__((ext_vector_type(4))) float  float4v;

__device__ __forceinline__ unsigned short f2bf(float f) {
  union { float f; unsigned u; } v; v.f = f;
  return (unsigned short)((v.u + 0x7FFFu + ((v.u >> 16) & 1u)) >> 16); // RNE
}
__device__ __forceinline__ float bf2f(unsigned short b) {
  union { unsigned u; float f; } v; v.u = ((unsigned)b) << 16;
  return v.f;
}

// async global->LDS, 16B per lane. dst must be wave-uniform; HW adds lane*16.
__device__ __forceinline__ void gload_lds16(const unsigned short* g, unsigned short* l) {
  __builtin_amdgcn_global_load_lds(
      (const __attribute__((address_space(1))) void*)g,
      (__attribute__((address_space(3))) void*)l, 16, 0, 0);
}

// ---------------- fp32 -> bf16 elementwise convert (vectorized) -------------
__global__ __launch_bounds__(256) void convert_f32_bf16(
    const float* __restrict__ src, unsigned short* __restrict__ dst, int n4) {
  int i = blockIdx.x * blockDim.x + threadIdx.x;
  int stride = gridDim.x * blockDim.x;
  for (; i < n4; i += stride) {
    float4v v = *(const float4v*)(src + (size_t)i * 4);
    short4v o;
#pragma unroll
    for (int j = 0; j < 4; ++j) o[j] = (short)f2bf(v[j]);
    *(short4v*)(dst + (size_t)i * 4) = o;
  }
}

// ---------------- fp32 [K][N] -> bf16 [N][K] tiled transpose ----------------
__global__ __launch_bounds__(256) void transpose_convert(
    const float* __restrict__ src, unsigned short* __restrict__ dst,
    int K, int N) {
  __shared__ float tile[64][65];
  int k0 = blockIdx.y * 64, n0 = blockIdx.x * 64;
  int tc = threadIdx.x & 63, tr = threadIdx.x >> 6;  // tr in 0..3
#pragma unroll
  for (int i = 0; i < 16; ++i) {
    int r = tr + 4 * i;
    tile[r][tc] = src[(size_t)(k0 + r) * N + n0 + tc];
  }
  __syncthreads();
#pragma unroll
  for (int i = 0; i < 16; ++i) {
    int r = tr + 4 * i;
    dst[(size_t)(n0 + r) * K + k0 + tc] = f2bf(tile[tc][r]);
  }
}

// ---- bf16 [T][6144] (v slice) -> bf16 [1024][T] tiled transpose ------------
__global__ __launch_bounds__(256) void v_transpose(
    const unsigned short* __restrict__ qkv, unsigned short* __restrict__ vt) {
  __shared__ unsigned short tile[64][72];
  int t0 = blockIdx.x * 64, e0 = blockIdx.y * 64;
  int tid = threadIdx.x;
  int lrow = tid >> 4, lcol = (tid & 15) * 4;
#pragma unroll
  for (int i = 0; i < 4; ++i) {
    int r = i * 16 + lrow;   // token row
    *(short4v*)&tile[r][lcol] =
        *(const short4v*)&qkv[(size_t)(t0 + r) * NQKVC + 5120 + e0 + lcol];
  }
  __syncthreads();
  int tc = tid & 63, tr = tid >> 6;
#pragma unroll
  for (int i = 0; i < 16; ++i) {
    int e = tr + 4 * i;
    vt[(size_t)(e0 + e) * TK + t0 + tc] = tile[tc][e];
  }
}

// ---------------- bf16 GEMM: C[M][N] = A[M][K] * BT[N][K]^T -----------------
// m97 structure: 128x128 tile, BK=64, 4 waves (2x2), global_load_lds staging.
// LDS XOR-swizzle (rule 21, both-sides): LDS[row][cp] = G[row][cp^(row&7)].
template <typename OutT>
__global__ __launch_bounds__(256) void gemm_bt(
    const unsigned short* __restrict__ A,   // [M][K] bf16
    const unsigned short* __restrict__ BT,  // [N][K] bf16
    OutT* __restrict__ C,                   // [M][N]
    int M, int N, int K) {
  __shared__ unsigned short As[128][64];
  __shared__ unsigned short Bs[128][64];
  int m0 = blockIdx.y * 128, n0 = blockIdx.x * 128;
  int tid = threadIdx.x;
  int lane = tid & 63, w = tid >> 6;
  int wr = (w >> 1) * 64, wc = (w & 1) * 64;   // wave's 64x64 sub-tile
  int lr = lane & 15, lg = lane >> 4;          // fragment row / k-group
  int srow = lane >> 3;                        // staging row within 8-row call
  int scol = ((lane & 7) ^ (srow & 7)) * 8;    // inverse-swizzled source chunk

  float4v acc[4][4] = {};

  for (int k0 = 0; k0 < K; k0 += 64) {
#pragma unroll
    for (int i = 0; i < 4; ++i) {
      int row = w * 32 + i * 8;
      gload_lds16(A + (size_t)(m0 + row + srow) * K + k0 + scol, &As[row][0]);
      gload_lds16(BT + (size_t)(n0 + row + srow) * K + k0 + scol, &Bs[row][0]);
    }
    __syncthreads();   // drains vmcnt -> tiles visible
#pragma unroll
    for (int kk = 0; kk < 64; kk += 32) {
      int cc = (((kk >> 3) + lg) ^ (lr & 7)) * 8;
      short8 a[4], b[4];
#pragma unroll
      for (int mi = 0; mi < 4; ++mi) a[mi] = *(const short8*)&As[wr + mi * 16 + lr][cc];
#pragma unroll
      for (int ni = 0; ni < 4; ++ni) b[ni] = *(const short8*)&Bs[wc + ni * 16 + lr][cc];
#pragma unroll
      for (int mi = 0; mi < 4; ++mi)
#pragma unroll
        for (int ni = 0; ni < 4; ++ni)
          acc[mi][ni] = __builtin_amdgcn_mfma_f32_16x16x32_bf16(a[mi], b[ni], acc[mi][ni], 0, 0, 0);
    }
    __syncthreads();
  }

  // epilogue: C/D layout col = lane&15, row = (lane>>4)*4 + r  [m89-verified]
  int orow = (lane >> 4) * 4;
#pragma unroll
  for (int mi = 0; mi < 4; ++mi)
#pragma unroll
    for (int ni = 0; ni < 4; ++ni)
#pragma unroll
      for (int r = 0; r < 4; ++r) {
        float v = acc[mi][ni][r];
        size_t idx = (size_t)(m0 + wr + mi * 16 + orow + r) * N + n0 + wc + ni * 16 + lr;
        if constexpr (std::is_same<OutT, unsigned short>::value)
          C[idx] = f2bf(v);
        else
          C[idx] = v;
      }
}

// ---------------- RoPE + KV-cache scatter + layout producers ----------------
// r5: q is written PRE-SCALED by scale*log2(e) so attn's softmax runs in
// exp2 domain with no per-element scaling (k/cache outputs stay unscaled).
__global__ __launch_bounds__(256) void rope_scatter(
    const unsigned short* __restrict__ qkv,   // [T][6144]
    const float* __restrict__ cosb,           // [T][64]
    const float* __restrict__ sinb,           // [T][64]
    const int* __restrict__ slots,
    unsigned short* __restrict__ qout,        // [T][4096]
    unsigned short* __restrict__ kout,        // [T][1024]
    float* __restrict__ kcache,               // [NSLOTS][1024] (output)
    float* __restrict__ vcache) {             // [NSLOTS][1024] (output)
  const float SC2 = 0.08838834764831845f * 1.4426950408889634f;  // scale*log2e
  int t = blockIdx.x;
  int tid = threadIdx.x;
  int slot = slots[t];
  const unsigned short* row = qkv + (size_t)t * NQKVC;

#pragma unroll
  for (int i = 0; i < 8; ++i) {
    int p = tid + 256 * i;
    int h = p >> 6, d = p & 63;
    float x1 = bf2f(row[h * 128 + d]);
    float x2 = bf2f(row[h * 128 + d + 64]);
    float c = cosb[t * 64 + d], s = sinb[t * 64 + d];
    qout[(size_t)t * HIDDEN + h * 128 + d]      = f2bf((x1 * c - x2 * s) * SC2);
    qout[(size_t)t * HIDDEN + h * 128 + d + 64] = f2bf((x2 * c + x1 * s) * SC2);
  }
#pragma unroll
  for (int i = 0; i < 2; ++i) {
    int p = tid + 256 * i;
    int kh = p >> 6, d = p & 63;
    float x1 = bf2f(row[4096 + kh * 128 + d]);
    float x2 = bf2f(row[4096 + kh * 128 + d + 64]);
    float c = cosb[t * 64 + d], s = sinb[t * 64 + d];
    float o1 = x1 * c - x2 * s, o2 = x2 * c + x1 * s;
    kout[t * 1024 + kh * 128 + d]      = f2bf(o1);
    kout[t * 1024 + kh * 128 + d + 64] = f2bf(o2);
    kcache[(size_t)slot * 1024 + kh * 128 + d]      = o1;
    kcache[(size_t)slot * 1024 + kh * 128 + d + 64] = o2;
  }
#pragma unroll
  for (int i = 0; i < 4; ++i) {
    int e = tid + 256 * i;
    vcache[(size_t)slot * 1024 + e] = bf2f(row[5120 + e]);
  }
}

// ---------------- flash attention (causal, GQA) -----------------------------
// grid (16, 32); block = 4 waves; q-tiles (31-bx, bx) paired -> 33 KV-iters.
// r5: KVBLK=64 (half the softmax/rescale/barrier overhead per kv), exp2-domain
// softmax (q pre-scaled), defer-max rescale (T13, THR=8), s_setprio around
// MFMA clusters (T5). K/V via global_load_lds, rule-21 XOR swizzle both sides.
__global__ __launch_bounds__(256) void attn_kernel(
    const unsigned short* __restrict__ q,    // [T][H][D] pre-scaled
    const unsigned short* __restrict__ k,    // [T][KVH][D]
    const unsigned short* __restrict__ vt,   // [KVH*D][T]
    unsigned short* __restrict__ attn) {     // [T][H*D]
  __shared__ unsigned short Ks[2][64][128];  // swizzle chunk^=(row&7), 32KB
  __shared__ unsigned short Vs[2][128][64];  // swizzle chunk^=(row&7), 32KB
  __shared__ unsigned short Ps[4][16][72];   // per-wave P relayout, 9KB

  const int h = blockIdx.y;
  const int g = h >> 2;                      // kv head
  const int tid = threadIdx.x, lane = tid & 63, w = tid >> 6;
  const int lr = lane & 15, lg = lane >> 4;

  // staging lane decompositions (dst linear; source pre-swizzled, rule 21)
  const int ksrow = lane >> 4;                      // K: 4 rows per 1KB call
  const int vsrow = lane >> 3;                      // V: 8 rows per 1KB call
  const int vscc  = ((lane & 7) ^ (vsrow & 7)) * 8; // v-row base %8==0

  for (int half = 0; half < 2; ++half) {
    const int q0 = (half == 0 ? (31 - (int)blockIdx.x) : (int)blockIdx.x) * 64;
    const int nt = (q0 >> 6) + 1;

    short8 qf[4];
    int qrow = q0 + w * 16 + lr;
#pragma unroll
    for (int c = 0; c < 4; ++c)
      qf[c] = *(const short8*)(q + (size_t)qrow * HIDDEN + h * DH + c * 32 + lg * 8);

    float4v accO[8] = {};
    float m[4], l[4];
#pragma unroll
    for (int r = 0; r < 4; ++r) { m[r] = -1e30f; l[r] = 0.f; }

    // prologue: stage tile 0 into buf 0 (K: 16 rows/wave, V: 32 rows/wave)
#pragma unroll
    for (int i = 0; i < 4; ++i) {
      int krow = w * 16 + i * 4;
      int kcc = ((lane & 15) ^ ((krow + ksrow) & 7)) * 8;
      gload_lds16(k + ((size_t)(krow + ksrow) * NKV + g) * DH + kcc, &Ks[0][krow][0]);
      int vrow = w * 32 + i * 8;
      gload_lds16(vt + (size_t)(g * DH + vrow + vsrow) * TK + vscc, &Vs[0][vrow][0]);
    }

    int cur = 0;
    for (int it = 0; it < nt; ++it) {
      int kv0 = it << 6;
      __syncthreads();  // drains vmcnt: buf[cur] staged; prev compute done
      if (it + 1 < nt) {
        int kv1 = kv0 + 64;
#pragma unroll
        for (int i = 0; i < 4; ++i) {
          int krow = w * 16 + i * 4;
          int kcc = ((lane & 15) ^ ((krow + ksrow) & 7)) * 8;
          gload_lds16(k + ((size_t)(kv1 + krow + ksrow) * NKV + g) * DH + kcc,
                      &Ks[cur ^ 1][krow][0]);
          int vrow = w * 32 + i * 8;
          gload_lds16(vt + (size_t)(g * DH + vrow + vsrow) * TK + kv1 + vscc,
                      &Vs[cur ^ 1][vrow][0]);
        }
      }

      // S = Q K^T : 4 col-tiles (kv j*16..j*16+15), swizzled chunks
      float4v s[4] = {};
      __builtin_amdgcn_s_setprio(1);
#pragma unroll
      for (int c = 0; c < 4; ++c) {
        int cc = ((c * 4 + lg) ^ (lr & 7)) * 8;   // (jt*16+lr)&7 == lr&7
#pragma unroll
        for (int jt = 0; jt < 4; ++jt) {
          short8 b = *(const short8*)&Ks[cur][jt * 16 + lr][cc];
          s[jt] = __builtin_amdgcn_mfma_f32_16x16x32_bf16(qf[c], b, s[jt], 0, 0, 0);
        }
      }
      __builtin_amdgcn_s_setprio(0);

      // online softmax (exp2 domain); acc row i = lg*4 + r, col j = lr
      int qg = q0 + w * 16 + lg * 4;
      bool domask = (kv0 + 63 > q0 + w * 16);
#pragma unroll
      for (int r = 0; r < 4; ++r) {
        float v0 = s[0][r], v1 = s[1][r], v2 = s[2][r], v3 = s[3][r];
        if (domask) {
          if (kv0 + lr      > qg + r) v0 = -1e30f;
          if (kv0 + 16 + lr > qg + r) v1 = -1e30f;
          if (kv0 + 32 + lr > qg + r) v2 = -1e30f;
          if (kv0 + 48 + lr > qg + r) v3 = -1e30f;
        }
        float mt = fmaxf(fmaxf(v0, v1), fmaxf(v2, v3));
#pragma unroll
        for (int msk = 8; msk >= 1; msk >>= 1) mt = fmaxf(mt, __shfl_xor(mt, msk));
        if (__any(mt > m[r] + 8.f)) {       // defer-max: rescale only on growth
          float mn = fmaxf(m[r], mt);
          float f = exp2f(m[r] - mn);
          m[r] = mn;
          l[r] *= f;
#pragma unroll
          for (int ni = 0; ni < 8; ++ni) accO[ni][r] *= f;
        }
        float p0 = exp2f(v0 - m[r]), p1 = exp2f(v1 - m[r]);
        float p2 = exp2f(v2 - m[r]), p3 = exp2f(v3 - m[r]);
        float rs = (p0 + p1) + (p2 + p3);
#pragma unroll
        for (int msk = 8; msk >= 1; msk >>= 1) rs += __shfl_xor(rs, msk);
        l[r] += rs;
        Ps[w][lg * 4 + r][lr]      = f2bf(p0);
        Ps[w][lg * 4 + r][16 + lr] = f2bf(p1);
        Ps[w][lg * 4 + r][32 + lr] = f2bf(p2);
        Ps[w][lg * 4 + r][48 + lr] = f2bf(p3);
      }

      // PV: A = P (16x64), B = V^T tile (swizzled), 2 k-chunks of 32
      short8 pa0 = *(const short8*)&Ps[w][lr][lg * 8];
      short8 pa1 = *(const short8*)&Ps[w][lr][32 + lg * 8];
      int cc0 = ((0 * 4 + lg) ^ (lr & 7)) * 8;
      int cc1 = ((1 * 4 + lg) ^ (lr & 7)) * 8;
      __builtin_amdgcn_s_setprio(1);
#pragma unroll
      for (int ni = 0; ni < 8; ++ni) {
        short8 bv0 = *(const short8*)&Vs[cur][ni * 16 + lr][cc0];
        short8 bv1 = *(const short8*)&Vs[cur][ni * 16 + lr][cc1];
        accO[ni] = __builtin_amdgcn_mfma_f32_16x16x32_bf16(pa0, bv0, accO[ni], 0, 0, 0);
        accO[ni] = __builtin_amdgcn_mfma_f32_16x16x32_bf16(pa1, bv1, accO[ni], 0, 0, 0);
      }
      __builtin_amdgcn_s_setprio(0);
      cur ^= 1;
    }
    __syncthreads();  // all LDS reads done before next half re-stages

    // epilogue: out[i][d], i = lg*4+r, d = ni*16+lr
#pragma unroll
    for (int ni = 0; ni < 8; ++ni)
#pragma unroll
      for (int r = 0; r < 4; ++r) {
        int row = q0 + w * 16 + lg * 4 + r;
        attn[(size_t)row * HIDDEN + h * DH + ni * 16 + lr] = f2bf(accO[ni][r] / l[r]);
      }
  }
}

// ---------------------------------------------------------------------------
extern "C" void kernel_launch(void* const* d_in, const int* in_sizes, int n_in,
                              void* d_out, int out_size, void* d_ws, size_t ws_size,
                              hipStream_t stream) {
  const float* hidden  = (const float*)d_in[0];
  const float* cosb    = (const float*)d_in[1];
  const float* sinb    = (const float*)d_in[2];
  const float* w_qkv   = (const float*)d_in[3];
  const float* w_o     = (const float*)d_in[4];
  const float* k_cache = (const float*)d_in[5];
  const float* v_cache = (const float*)d_in[6];
  const int*   slots   = (const int*)d_in[7];

  float* out = (float*)d_out;                         // [T][HIDDEN]
  float* kco = out + (size_t)TK * HIDDEN;             // [NSLOTS][NKV][DH]
  float* vco = kco + (size_t)NSLOTS * NKV * DH;

  // workspace layout (bytes); total 144 MB
  char* ws = (char*)d_ws;
  const size_t MB = 1024 * 1024;
  unsigned short* hid_bf = (unsigned short*)(ws + 0);         // 16 MB
  unsigned short* wqkvT  = (unsigned short*)(ws + 16 * MB);   // 48 MB [6144][4096]
  unsigned short* woT    = (unsigned short*)(ws + 64 * MB);   // 32 MB [4096][4096]
  unsigned short* qkvb   = (unsigned short*)(ws + 96 * MB);   // 24 MB [T][6144]
  unsigned short* qb     = (unsigned short*)(ws + 120 * MB);  // 16 MB
  unsigned short* kb     = (unsigned short*)(ws + 136 * MB);  //  4 MB
  unsigned short* vtb    = (unsigned short*)(ws + 140 * MB);  //  4 MB
  unsigned short* attnb  = hid_bf;  // reuse: hidden_bf16 dead after QKV GEMM

  // 1) convert inputs to bf16 (+ transpose weights to [N][K])
  convert_f32_bf16<<<2048, 256, 0, stream>>>(hidden, hid_bf, TK * HIDDEN / 4);
  transpose_convert<<<dim3(NQKVC / 64, HIDDEN / 64), 256, 0, stream>>>(
      w_qkv, wqkvT, HIDDEN, NQKVC);
  transpose_convert<<<dim3(HIDDEN / 64, HIDDEN / 64), 256, 0, stream>>>(
      w_o, woT, HIDDEN, HIDDEN);

  // 2) QKV GEMM: [2048][4096] x [4096][6144] -> bf16 [2048][6144]
  gemm_bt<unsigned short><<<dim3(NQKVC / 128, TK / 128), 256, 0, stream>>>(
      hid_bf, wqkvT, qkvb, TK, NQKVC, HIDDEN);

  // 3) cache passthrough copies (d_out is re-poisoned each call)
  hipMemcpyAsync(kco, k_cache, (size_t)NSLOTS * NKV * DH * 4,
                 hipMemcpyDeviceToDevice, stream);
  hipMemcpyAsync(vco, v_cache, (size_t)NSLOTS * NKV * DH * 4,
                 hipMemcpyDeviceToDevice, stream);

  // 4) RoPE + cache scatter; V transpose for PV B-operand layout
  rope_scatter<<<TK, 256, 0, stream>>>(qkvb, cosb, sinb, slots,
                                       qb, kb, kco, vco);
  v_transpose<<<dim3(TK / 64, 16), 256, 0, stream>>>(qkvb, vtb);

  // 5) flash attention (paired q-tiles for causal load balance)
  attn_kernel<<<dim3(16, NHEAD), 256, 0, stream>>>(qb, kb, vtb, attnb);

  // 6) output GEMM: [2048][4096] x [4096][4096] -> fp32 d_out
  gemm_bt<float><<<dim3(HIDDEN / 128, TK / 128), 256, 0, stream>>>(
      attnb, woT, out, TK, HIDDEN, HIDDEN);
}